// Round 15
// baseline (91.365 us; speedup 1.0000x reference)
//
#include <hip/hip_runtime.h>
#include <hip/hip_bf16.h>
#include <stdint.h>

// Problem dims (fixed by reference)
#define R_TOTAL 1024      // B*S
#define I_DIM   4096
#define OUT_DIM 4096
#define N_STR   32
#define Q_DIM   128

typedef __attribute__((ext_vector_type(8))) __bf16 bf16x8;
typedef __attribute__((ext_vector_type(4))) float  f32x4;

__device__ __forceinline__ ushort f2bf(float f) {
    uint32_t u = __float_as_uint(f);
    uint32_t r = (u + 0x7fffu + ((u >> 16) & 1u)) >> 16;   // RNE
    return (ushort)r;
}

__device__ __forceinline__ float bf2f(ushort u) {
    return __uint_as_float((uint32_t)u << 16);
}

// gate two fp32 lanes (exact fp32 compare, as reference) and pack to 2 bf16
// via v_cvt_pk_bf16_f32 (RNE; dst.lo = src0, dst.hi = src1 — T12 recipe).
__device__ __forceinline__ uint32_t gate_pk(float x0, float x1,
                                            float m0, float m1,
                                            float t0, float t1) {
    float a = x0 - m0, b = x1 - m1;
    float ga = (fabsf(a) >= t0) ? a : 0.f;
    float gb = (fabsf(b) >= t1) ? b : 0.f;
    uint32_t r;
    asm("v_cvt_pk_bf16_f32 %0, %1, %2" : "=v"(r) : "v"(ga), "v"(gb));
    return r;
}

__device__ __forceinline__ void async16(void* lds, const void* g) {
    __builtin_amdgcn_global_load_lds(
        (const __attribute__((address_space(1))) unsigned int*)g,
        (__attribute__((address_space(3))) unsigned int*)lds, 16, 0, 0);
}

// ================= pre-pass bodies ===========================================

// W [I][OUT] f32 -> WT [OUT][I] bf16, one 64x64 tile
__device__ __forceinline__ void transpose_w_block(const float* __restrict__ W,
                                                  ushort* __restrict__ WT,
                                                  int c0, int i0, int t,
                                                  float (*tile)[65]) {
    {
        int dc4 = (t & 15) * 4;
        int di  = t >> 4;
        #pragma unroll
        for (int p = 0; p < 4; ++p) {
            int ii = di + p * 16;
            float4 v = *(const float4*)(W + (size_t)(i0 + ii) * OUT_DIM + c0 + dc4);
            tile[ii][dc4 + 0] = v.x; tile[ii][dc4 + 1] = v.y;
            tile[ii][dc4 + 2] = v.z; tile[ii][dc4 + 3] = v.w;
        }
    }
    __syncthreads();
    {
        int iq = (t & 15) * 4;
        int dc = t >> 4;
        #pragma unroll
        for (int p = 0; p < 4; ++p) {
            int cc = dc + p * 16;
            ushort4 o;
            o.x = f2bf(tile[iq + 0][cc]);
            o.y = f2bf(tile[iq + 1][cc]);
            o.z = f2bf(tile[iq + 2][cc]);
            o.w = f2bf(tile[iq + 3][cc]);
            *(ushort4*)(WT + (size_t)(c0 + cc) * I_DIM + i0 + iq) = o;
        }
    }
}

// th [I][N] f32 -> thT [N][I] f32, one 64(i) x 32(n) tile via LDS
__device__ __forceinline__ void transpose_th_block(const float* __restrict__ th,
                                                   float* __restrict__ thT,
                                                   int i0, int t, float* tile) {
    {
        int ri = t >> 2;
        int nc = (t & 3) * 8;
        float4 v0 = *(const float4*)(th + (size_t)(i0 + ri) * N_STR + nc);
        float4 v1 = *(const float4*)(th + (size_t)(i0 + ri) * N_STR + nc + 4);
        tile[ri * 33 + nc + 0] = v0.x; tile[ri * 33 + nc + 1] = v0.y;
        tile[ri * 33 + nc + 2] = v0.z; tile[ri * 33 + nc + 3] = v0.w;
        tile[ri * 33 + nc + 4] = v1.x; tile[ri * 33 + nc + 5] = v1.y;
        tile[ri * 33 + nc + 6] = v1.z; tile[ri * 33 + nc + 7] = v1.w;
    }
    __syncthreads();
    {
        int n  = t >> 3;
        int di = (t & 7) * 8;
        float4 o0, o1;
        o0.x = tile[(di + 0) * 33 + n]; o0.y = tile[(di + 1) * 33 + n];
        o0.z = tile[(di + 2) * 33 + n]; o0.w = tile[(di + 3) * 33 + n];
        o1.x = tile[(di + 4) * 33 + n]; o1.y = tile[(di + 5) * 33 + n];
        o1.z = tile[(di + 6) * 33 + n]; o1.w = tile[(di + 7) * 33 + n];
        *(float4*)(thT + (size_t)n * I_DIM + i0 + di) = o0;
        *(float4*)(thT + (size_t)n * I_DIM + i0 + di + 4) = o1;
    }
}

// ---------------- merged pre-pass: th-transpose (0..63) + W-transpose --------
__global__ __launch_bounds__(256) void k_prep7(const float* __restrict__ W,
                                               ushort* __restrict__ WT,
                                               const float* __restrict__ th,
                                               float* __restrict__ thT) {
    __shared__ __align__(16) float smem[64 * 65];
    int b = blockIdx.x;
    int t = threadIdx.x;
    if (b < 64) {
        transpose_th_block(th, thT, b * 64, t, smem);
    } else {
        int tb = b - 64;
        transpose_w_block(W, WT, (tb & 63) * 64, (tb >> 6) * 64, t,
                          (float (*)[65])smem);
    }
}

// ---------------- main v13: XCD = row-tile mapping (x L2-resident) -----------
// Identical structure to v12 (inline gate, phase-1 x issue, 3 blocks/CU,
// split-K=3 22/21/21). Only the bid->(rt,n,kq) map changes: xcd carries rt,
// so one XCD's 96 blocks (32 stripes x 3 kq) share the SAME 128 x rows:
// unique x per XCD = 128*4096*4B = 2 MB -> L2-resident. The barrier-1
// vmcnt(0) drain then pays ~200cy (L2) instead of ~900cy (L3) for x.

#define LOADX(XA, OFF)                                              \
    do {                                                            \
        _Pragma("unroll")                                           \
        for (int p = 0; p < 4; ++p) {                               \
            XA[p][0] = *(const float4*)(pX[p] + (OFF));             \
            XA[p][1] = *((const float4*)(pX[p] + (OFF)) + 1);       \
        }                                                           \
    } while (0)

#define GATEW(XA)                                                                        \
    do {                                                                                 \
        _Pragma("unroll")                                                                \
        for (int p = 0; p < 4; ++p) {                                                    \
            uint4 z;                                                                     \
            z.x = gate_pk(XA[p][0].x, XA[p][0].y, muv[0].x, muv[0].y, thv[0].x, thv[0].y); \
            z.y = gate_pk(XA[p][0].z, XA[p][0].w, muv[0].z, muv[0].w, thv[0].z, thv[0].w); \
            z.z = gate_pk(XA[p][1].x, XA[p][1].y, muv[1].x, muv[1].y, thv[1].x, thv[1].y); \
            z.w = gate_pk(XA[p][1].z, XA[p][1].w, muv[1].z, muv[1].w, thv[1].z, thv[1].w); \
            *(uint4*)((char*)sA + awz[p]) = z;                                           \
        }                                                                                \
    } while (0)

__global__ __launch_bounds__(256, 3) void k_main13(const float* __restrict__ x,
                                                   const ushort* __restrict__ WT,
                                                   const float* __restrict__ thT,
                                                   const float* __restrict__ mu,
                                                   ushort* __restrict__ PB0,
                                                   ushort* __restrict__ PB1,
                                                   ushort* __restrict__ PB2) {
    __shared__ ushort sA[128 * 64];      // 16 KB (single)
    __shared__ ushort sB[2][128 * 64];   // 16 KB each

    int bid  = blockIdx.x;               // 0..767
    int rt   = bid & 7;                  // row tile == XCD (x L2-residency)
    int slot = bid >> 3;                 // 0..95
    int n    = slot & 31;                // stripe
    int kq   = slot >> 5;                // 0..2
    int r0   = rt * 128;
    int k0   = (kq == 0) ? 0 : (kq == 1) ? 1408 : 2752;
    int NT   = (kq == 0) ? 22 : 21;
    int cbase = n * Q_DIM;
    ushort* P = (kq == 0) ? PB0 : (kq == 1) ? PB1 : PB2;

    int tid  = threadIdx.x;
    int lane = tid & 63;
    int wave = tid >> 6;                 // 0..3
    int wr   = wave >> 1;                // 0..1 : 64-row group
    int wc   = wave & 1;                 // 0..1 : 64-col group
    int lrow = lane & 15;
    int lgrp = lane >> 4;

    // ---- A staging maps: pass p: row = p*32 + (tid>>3), 8 consecutive k
    const float* pX[4];
    int awz[4];
    const int ak = (tid & 7) * 8;
    {
        int ar = tid >> 3;
        #pragma unroll
        for (int p = 0; p < 4; ++p) {
            int row = p * 32 + ar;
            pX[p] = x + (size_t)(r0 + row) * I_DIM + k0 + ak;
            awz[p] = row * 128 + ((ak * 2) ^ ((row & 7) << 4));
        }
    }
    const float* pTH = thT + (size_t)n * I_DIM + k0 + ak;
    const float* pMU = mu + k0 + ak;

    // ---- B staging maps: 16 chunks of 1KB; pre-swizzled source
    const char* pBq[4];
    int ldsBo[4];
    #pragma unroll
    for (int q = 0; q < 4; ++q) {
        int chunk = wave * 4 + q;
        int col = chunk * 8 + (lane >> 3);
        pBq[q] = (const char*)WT + (size_t)(cbase + col) * (I_DIM * 2)
               + (size_t)k0 * 2 + (((lane & 7) ^ (lane >> 3)) << 4);
        ldsBo[q] = chunk * 1024;
    }

    f32x4 acc[4][4];
    #pragma unroll
    for (int m2 = 0; m2 < 4; ++m2)
        #pragma unroll
        for (int nn = 0; nn < 4; ++nn)
            acc[m2][nn] = (f32x4){0.f, 0.f, 0.f, 0.f};

    float4 xa[4][2], thv[2], muv[2];     // single-depth A-regs (phase1 -> phase2)

    // ---- prologue: A(0) regs + th/mu(0); B0 DMA; gate+write sA(0); barrier
    LOADX(xa, 0);
    thv[0] = *(const float4*)pTH; thv[1] = *((const float4*)pTH + 1);
    muv[0] = *(const float4*)pMU; muv[1] = *((const float4*)pMU + 1);
    #pragma unroll
    for (int q = 0; q < 4; ++q) async16((char*)sB[0] + ldsBo[q], pBq[q]);
    GATEW(xa);                           // write sA(0)
    __syncthreads();                     // sA(0), sB[0] ready

    for (int t = 0; t < NT; ++t) {
        // ---- phase 1: issue B(t+1) DMA AND A(t+1) x/th/mu loads; then compute
        if (t + 1 < NT) {
            #pragma unroll
            for (int q = 0; q < 4; ++q)
                async16((char*)sB[(t + 1) & 1] + ldsBo[q],
                        pBq[q] + (size_t)(t + 1) * 128);
            int o1 = (t + 1) * 64;
            LOADX(xa, o1);
            thv[0] = *(const float4*)(pTH + o1);
            thv[1] = *((const float4*)(pTH + o1) + 1);
            muv[0] = *(const float4*)(pMU + o1);
            muv[1] = *((const float4*)(pMU + o1) + 1);
        }
        // ---- compute tile t (sA single, sB[t&1]) — covers the loads above
        const char* sAc = (const char*)sA;
        const char* sBc = (const char*)sB[t & 1];
        __builtin_amdgcn_s_setprio(1);
        #pragma unroll
        for (int ks = 0; ks < 2; ++ks) {
            int kb = ks * 64 + (lgrp << 4);
            bf16x8 af[4], bfr[4];
            #pragma unroll
            for (int m2 = 0; m2 < 4; ++m2) {
                int row = wr * 64 + m2 * 16 + lrow;
                af[m2] = *(const bf16x8*)(sAc + row * 128 + (kb ^ ((row & 7) << 4)));
            }
            #pragma unroll
            for (int nn = 0; nn < 4; ++nn) {
                int col = wc * 64 + nn * 16 + lrow;
                bfr[nn] = *(const bf16x8*)(sBc + col * 128 + (kb ^ ((col & 7) << 4)));
            }
            #pragma unroll
            for (int m2 = 0; m2 < 4; ++m2)
                #pragma unroll
                for (int nn = 0; nn < 4; ++nn)
                    acc[m2][nn] = __builtin_amdgcn_mfma_f32_16x16x32_bf16(af[m2], bfr[nn], acc[m2][nn], 0, 0, 0);
        }
        __builtin_amdgcn_s_setprio(0);
        __syncthreads();                 // compute done; B(t+1) + xa drained
        // ---- phase 2: gate + write sA(t+1) (pure VALU + ds_write)
        if (t + 1 < NT) {
            GATEW(xa);
        }
        __syncthreads();                 // sA(t+1) visible (lgkm-only drain)
    }

    // ---- epilogue: bf16 partials (summed + out_mu added in k_reduce3b)
    #pragma unroll
    for (int nn = 0; nn < 4; ++nn) {
        int col = cbase + wc * 64 + nn * 16 + lrow;
        #pragma unroll
        for (int m2 = 0; m2 < 4; ++m2) {
            int rbase = r0 + wr * 64 + m2 * 16 + lgrp * 4;
            #pragma unroll
            for (int j = 0; j < 4; ++j)
                P[(size_t)(rbase + j) * OUT_DIM + col] = f2bf(acc[m2][nn][j]);
        }
    }
}

// ---------------- reduce: out = PB0 + PB1 + PB2 + out_mu (bf16 partials) -----
__global__ __launch_bounds__(256) void k_reduce3b(float* __restrict__ out,
                                                  const ushort* __restrict__ PB0,
                                                  const ushort* __restrict__ PB1,
                                                  const ushort* __restrict__ PB2,
                                                  const float* __restrict__ out_mu) {
    int idx = blockIdx.x * 256 + threadIdx.x;       // 8-elem group, 524288 total
    uint4 a = *(const uint4*)(PB0 + (size_t)idx * 8);
    uint4 b = *(const uint4*)(PB1 + (size_t)idx * 8);
    uint4 c = *(const uint4*)(PB2 + (size_t)idx * 8);
    const float* om = out_mu + (idx & 511) * 8;
    float4 m0 = *(const float4*)om;
    float4 m1 = *(const float4*)(om + 4);
    float4 o0, o1;
    o0.x = bf2f((ushort)(a.x & 0xFFFF)) + bf2f((ushort)(b.x & 0xFFFF)) + bf2f((ushort)(c.x & 0xFFFF)) + m0.x;
    o0.y = bf2f((ushort)(a.x >> 16))    + bf2f((ushort)(b.x >> 16))    + bf2f((ushort)(c.x >> 16))    + m0.y;
    o0.z = bf2f((ushort)(a.y & 0xFFFF)) + bf2f((ushort)(b.y & 0xFFFF)) + bf2f((ushort)(c.y & 0xFFFF)) + m0.z;
    o0.w = bf2f((ushort)(a.y >> 16))    + bf2f((ushort)(b.y >> 16))    + bf2f((ushort)(c.y >> 16))    + m0.w;
    o1.x = bf2f((ushort)(a.z & 0xFFFF)) + bf2f((ushort)(b.z & 0xFFFF)) + bf2f((ushort)(c.z & 0xFFFF)) + m1.x;
    o1.y = bf2f((ushort)(a.z >> 16))    + bf2f((ushort)(b.z >> 16))    + bf2f((ushort)(c.z >> 16))    + m1.y;
    o1.z = bf2f((ushort)(a.w & 0xFFFF)) + bf2f((ushort)(b.w & 0xFFFF)) + bf2f((ushort)(c.w & 0xFFFF)) + m1.z;
    o1.w = bf2f((ushort)(a.w >> 16))    + bf2f((ushort)(b.w >> 16))    + bf2f((ushort)(c.w >> 16))    + m1.w;
    float* dst = out + (size_t)idx * 8;
    *(float4*)dst = o0;
    *(float4*)(dst + 4) = o1;
}

// ---------------- fallback: naive fp32 ---------------------------------------
__global__ __launch_bounds__(256) void k_naive(const float* __restrict__ x,
                                               const float* __restrict__ W,
                                               const float* __restrict__ th,
                                               const float* __restrict__ mu,
                                               const float* __restrict__ out_mu,
                                               float* __restrict__ out) {
    int idx = blockIdx.x * 256 + threadIdx.x;
    int r = idx >> 12;
    int c = idx & 4095;
    int n = c >> 7;
    float s = 0.f;
    for (int i = 0; i < I_DIM; ++i) {
        float xo = x[(size_t)r * I_DIM + i] - mu[i];
        if (fabsf(xo) >= th[i * N_STR + n])
            s += xo * W[(size_t)i * OUT_DIM + c];
    }
    out[idx] = s + out_mu[c];
}

extern "C" void kernel_launch(void* const* d_in, const int* in_sizes, int n_in,
                              void* d_out, int out_size, void* d_ws, size_t ws_size,
                              hipStream_t stream) {
    const float* x      = (const float*)d_in[0];
    const float* W      = (const float*)d_in[1];
    const float* th     = (const float*)d_in[2];
    const float* mu     = (const float*)d_in[3];
    const float* out_mu = (const float*)d_in[4];
    float* out = (float*)d_out;

    const size_t wT_b  = (size_t)OUT_DIM * I_DIM * sizeof(ushort);   // 32 MiB
    const size_t thT_b = (size_t)N_STR * I_DIM * sizeof(float);      // 0.5 MiB
    const size_t pb_b  = (size_t)R_TOTAL * OUT_DIM * sizeof(ushort); // 8 MiB each

    ushort* WT  = (ushort*)d_ws;
    float*  thT = (float*)((char*)d_ws + wT_b);
    ushort* PB0 = (ushort*)((char*)d_ws + wT_b + thT_b);
    ushort* PB1 = (ushort*)((char*)d_ws + wT_b + thT_b + pb_b);
    ushort* PB2 = (ushort*)((char*)d_ws + wT_b + thT_b + 2 * pb_b);

    if (ws_size >= wT_b + thT_b + 3 * pb_b) {
        k_prep7<<<64 + 4096, 256, 0, stream>>>(W, WT, th, thT);
        k_main13<<<768, 256, 0, stream>>>(x, WT, thT, mu, PB0, PB1, PB2);
        k_reduce3b<<<(R_TOTAL * OUT_DIM / 8) / 256, 256, 0, stream>>>(out, PB0, PB1, PB2, out_mu);
    } else {
        k_naive<<<(R_TOTAL * OUT_DIM) / 256, 256, 0, stream>>>(x, W, th, mu, out_mu, out);
    }
}

// Round 16
// 85.534 us; speedup vs baseline: 1.0682x; 1.0682x over previous
//
#include <hip/hip_runtime.h>
#include <hip/hip_bf16.h>
#include <stdint.h>

// Problem dims (fixed by reference)
#define R_TOTAL 1024      // B*S
#define I_DIM   4096
#define OUT_DIM 4096
#define N_STR   32
#define Q_DIM   128

typedef __attribute__((ext_vector_type(8))) __bf16 bf16x8;
typedef __attribute__((ext_vector_type(4))) float  f32x4;

__device__ __forceinline__ ushort f2bf(float f) {
    uint32_t u = __float_as_uint(f);
    uint32_t r = (u + 0x7fffu + ((u >> 16) & 1u)) >> 16;   // RNE
    return (ushort)r;
}

__device__ __forceinline__ float bf2f(ushort u) {
    return __uint_as_float((uint32_t)u << 16);
}

// gate two fp32 lanes (exact fp32 compare, as reference) and pack to 2 bf16
// via v_cvt_pk_bf16_f32 (RNE; dst.lo = src0, dst.hi = src1 — T12 recipe).
__device__ __forceinline__ uint32_t gate_pk(float x0, float x1,
                                            float m0, float m1,
                                            float t0, float t1) {
    float a = x0 - m0, b = x1 - m1;
    float ga = (fabsf(a) >= t0) ? a : 0.f;
    float gb = (fabsf(b) >= t1) ? b : 0.f;
    uint32_t r;
    asm("v_cvt_pk_bf16_f32 %0, %1, %2" : "=v"(r) : "v"(ga), "v"(gb));
    return r;
}

__device__ __forceinline__ void async16(void* lds, const void* g) {
    __builtin_amdgcn_global_load_lds(
        (const __attribute__((address_space(1))) unsigned int*)g,
        (__attribute__((address_space(3))) unsigned int*)lds, 16, 0, 0);
}

// ================= pre-pass bodies ===========================================

// W [I][OUT] f32 -> WT [OUT][I] bf16, one 64x64 tile
__device__ __forceinline__ void transpose_w_block(const float* __restrict__ W,
                                                  ushort* __restrict__ WT,
                                                  int c0, int i0, int t,
                                                  float (*tile)[65]) {
    {
        int dc4 = (t & 15) * 4;
        int di  = t >> 4;
        #pragma unroll
        for (int p = 0; p < 4; ++p) {
            int ii = di + p * 16;
            float4 v = *(const float4*)(W + (size_t)(i0 + ii) * OUT_DIM + c0 + dc4);
            tile[ii][dc4 + 0] = v.x; tile[ii][dc4 + 1] = v.y;
            tile[ii][dc4 + 2] = v.z; tile[ii][dc4 + 3] = v.w;
        }
    }
    __syncthreads();
    {
        int iq = (t & 15) * 4;
        int dc = t >> 4;
        #pragma unroll
        for (int p = 0; p < 4; ++p) {
            int cc = dc + p * 16;
            ushort4 o;
            o.x = f2bf(tile[iq + 0][cc]);
            o.y = f2bf(tile[iq + 1][cc]);
            o.z = f2bf(tile[iq + 2][cc]);
            o.w = f2bf(tile[iq + 3][cc]);
            *(ushort4*)(WT + (size_t)(c0 + cc) * I_DIM + i0 + iq) = o;
        }
    }
}

// th [I][N] f32 -> thT [N][I] f32, one 64(i) x 32(n) tile via LDS
__device__ __forceinline__ void transpose_th_block(const float* __restrict__ th,
                                                   float* __restrict__ thT,
                                                   int i0, int t, float* tile) {
    {
        int ri = t >> 2;
        int nc = (t & 3) * 8;
        float4 v0 = *(const float4*)(th + (size_t)(i0 + ri) * N_STR + nc);
        float4 v1 = *(const float4*)(th + (size_t)(i0 + ri) * N_STR + nc + 4);
        tile[ri * 33 + nc + 0] = v0.x; tile[ri * 33 + nc + 1] = v0.y;
        tile[ri * 33 + nc + 2] = v0.z; tile[ri * 33 + nc + 3] = v0.w;
        tile[ri * 33 + nc + 4] = v1.x; tile[ri * 33 + nc + 5] = v1.y;
        tile[ri * 33 + nc + 6] = v1.z; tile[ri * 33 + nc + 7] = v1.w;
    }
    __syncthreads();
    {
        int n  = t >> 3;
        int di = (t & 7) * 8;
        float4 o0, o1;
        o0.x = tile[(di + 0) * 33 + n]; o0.y = tile[(di + 1) * 33 + n];
        o0.z = tile[(di + 2) * 33 + n]; o0.w = tile[(di + 3) * 33 + n];
        o1.x = tile[(di + 4) * 33 + n]; o1.y = tile[(di + 5) * 33 + n];
        o1.z = tile[(di + 6) * 33 + n]; o1.w = tile[(di + 7) * 33 + n];
        *(float4*)(thT + (size_t)n * I_DIM + i0 + di) = o0;
        *(float4*)(thT + (size_t)n * I_DIM + i0 + di + 4) = o1;
    }
}

// ---------------- merged pre-pass: th-transpose (0..63) + W-transpose --------
__global__ __launch_bounds__(256) void k_prep7(const float* __restrict__ W,
                                               ushort* __restrict__ WT,
                                               const float* __restrict__ th,
                                               float* __restrict__ thT) {
    __shared__ __align__(16) float smem[64 * 65];
    int b = blockIdx.x;
    int t = threadIdx.x;
    if (b < 64) {
        transpose_th_block(th, thT, b * 64, t, smem);
    } else {
        int tb = b - 64;
        transpose_w_block(W, WT, (tb & 63) * 64, (tb >> 6) * 64, t,
                          (float (*)[65])smem);
    }
}

// ---------------- main v14: R14 structure; phase-1 load order x -> B ---------
// tile 128x128, 4 waves of 64x64, BK=64. sA single (16K) + sB dbuf (32K)
// = 48 KB -> 3 blocks/CU. Split-K=3 uneven: 22/21/21 steps of BK=64.
// R14 map (xcd carries stripe-group: WT slice 4MB = L2-fit; R15's xcd=rt
// map regressed, FETCH 83->144MB). Change vs R14: in phase 1, issue the
// x/th/mu register loads BEFORE the B DMA. vmcnt is FIFO-ordered, so the
// gate's implicit wait on xa becomes vmcnt(4) (B DMAs stay in flight through
// GATEW) instead of vmcnt(0); the B DMAs are drained only at barrier-2,
// where the next compute needs them anyway.

#define LOADX(XA, OFF)                                              \
    do {                                                            \
        _Pragma("unroll")                                           \
        for (int p = 0; p < 4; ++p) {                               \
            XA[p][0] = *(const float4*)(pX[p] + (OFF));             \
            XA[p][1] = *((const float4*)(pX[p] + (OFF)) + 1);       \
        }                                                           \
    } while (0)

#define GATEW(XA)                                                                        \
    do {                                                                                 \
        _Pragma("unroll")                                                                \
        for (int p = 0; p < 4; ++p) {                                                    \
            uint4 z;                                                                     \
            z.x = gate_pk(XA[p][0].x, XA[p][0].y, muv[0].x, muv[0].y, thv[0].x, thv[0].y); \
            z.y = gate_pk(XA[p][0].z, XA[p][0].w, muv[0].z, muv[0].w, thv[0].z, thv[0].w); \
            z.z = gate_pk(XA[p][1].x, XA[p][1].y, muv[1].x, muv[1].y, thv[1].x, thv[1].y); \
            z.w = gate_pk(XA[p][1].z, XA[p][1].w, muv[1].z, muv[1].w, thv[1].z, thv[1].w); \
            *(uint4*)((char*)sA + awz[p]) = z;                                           \
        }                                                                                \
    } while (0)

__global__ __launch_bounds__(256, 3) void k_main14(const float* __restrict__ x,
                                                   const ushort* __restrict__ WT,
                                                   const float* __restrict__ thT,
                                                   const float* __restrict__ mu,
                                                   ushort* __restrict__ PB0,
                                                   ushort* __restrict__ PB1,
                                                   ushort* __restrict__ PB2) {
    __shared__ ushort sA[128 * 64];      // 16 KB (single)
    __shared__ ushort sB[2][128 * 64];   // 16 KB each

    int bid  = blockIdx.x;               // 0..767
    int xcd  = bid & 7;
    int slot = bid >> 3;                 // 0..95
    int n    = xcd * 4 + (slot & 3);     // stripe (XCD-local group of 4)
    int rt   = (slot >> 2) & 7;          // row tile 0..7
    int kq   = slot >> 5;                // 0..2
    int r0   = rt * 128;
    int k0   = (kq == 0) ? 0 : (kq == 1) ? 1408 : 2752;
    int NT   = (kq == 0) ? 22 : 21;
    int cbase = n * Q_DIM;
    ushort* P = (kq == 0) ? PB0 : (kq == 1) ? PB1 : PB2;

    int tid  = threadIdx.x;
    int lane = tid & 63;
    int wave = tid >> 6;                 // 0..3
    int wr   = wave >> 1;                // 0..1 : 64-row group
    int wc   = wave & 1;                 // 0..1 : 64-col group
    int lrow = lane & 15;
    int lgrp = lane >> 4;

    // ---- A staging maps: pass p: row = p*32 + (tid>>3), 8 consecutive k
    const float* pX[4];
    int awz[4];
    const int ak = (tid & 7) * 8;
    {
        int ar = tid >> 3;
        #pragma unroll
        for (int p = 0; p < 4; ++p) {
            int row = p * 32 + ar;
            pX[p] = x + (size_t)(r0 + row) * I_DIM + k0 + ak;
            awz[p] = row * 128 + ((ak * 2) ^ ((row & 7) << 4));
        }
    }
    const float* pTH = thT + (size_t)n * I_DIM + k0 + ak;
    const float* pMU = mu + k0 + ak;

    // ---- B staging maps: 16 chunks of 1KB; pre-swizzled source
    const char* pBq[4];
    int ldsBo[4];
    #pragma unroll
    for (int q = 0; q < 4; ++q) {
        int chunk = wave * 4 + q;
        int col = chunk * 8 + (lane >> 3);
        pBq[q] = (const char*)WT + (size_t)(cbase + col) * (I_DIM * 2)
               + (size_t)k0 * 2 + (((lane & 7) ^ (lane >> 3)) << 4);
        ldsBo[q] = chunk * 1024;
    }

    f32x4 acc[4][4];
    #pragma unroll
    for (int m2 = 0; m2 < 4; ++m2)
        #pragma unroll
        for (int nn = 0; nn < 4; ++nn)
            acc[m2][nn] = (f32x4){0.f, 0.f, 0.f, 0.f};

    float4 xa[4][2], thv[2], muv[2];     // single-depth A-regs (phase1 -> phase2)

    // ---- prologue: A(0) regs + th/mu(0) FIRST; then B0 DMA; gate; barrier
    LOADX(xa, 0);
    thv[0] = *(const float4*)pTH; thv[1] = *((const float4*)pTH + 1);
    muv[0] = *(const float4*)pMU; muv[1] = *((const float4*)pMU + 1);
    #pragma unroll
    for (int q = 0; q < 4; ++q) async16((char*)sB[0] + ldsBo[q], pBq[q]);
    GATEW(xa);                           // write sA(0)
    __syncthreads();                     // sA(0), sB[0] ready

    for (int t = 0; t < NT; ++t) {
        // ---- phase 1: A(t+1) x/th/mu loads FIRST, then B(t+1) DMA; compute
        if (t + 1 < NT) {
            int o1 = (t + 1) * 64;
            LOADX(xa, o1);
            thv[0] = *(const float4*)(pTH + o1);
            thv[1] = *((const float4*)(pTH + o1) + 1);
            muv[0] = *(const float4*)(pMU + o1);
            muv[1] = *((const float4*)(pMU + o1) + 1);
            #pragma unroll
            for (int q = 0; q < 4; ++q)
                async16((char*)sB[(t + 1) & 1] + ldsBo[q],
                        pBq[q] + (size_t)(t + 1) * 128);
        }
        // ---- compute tile t (sA single, sB[t&1]) — covers the loads above
        const char* sAc = (const char*)sA;
        const char* sBc = (const char*)sB[t & 1];
        __builtin_amdgcn_s_setprio(1);
        #pragma unroll
        for (int ks = 0; ks < 2; ++ks) {
            int kb = ks * 64 + (lgrp << 4);
            bf16x8 af[4], bfr[4];
            #pragma unroll
            for (int m2 = 0; m2 < 4; ++m2) {
                int row = wr * 64 + m2 * 16 + lrow;
                af[m2] = *(const bf16x8*)(sAc + row * 128 + (kb ^ ((row & 7) << 4)));
            }
            #pragma unroll
            for (int nn = 0; nn < 4; ++nn) {
                int col = wc * 64 + nn * 16 + lrow;
                bfr[nn] = *(const bf16x8*)(sBc + col * 128 + (kb ^ ((col & 7) << 4)));
            }
            #pragma unroll
            for (int m2 = 0; m2 < 4; ++m2)
                #pragma unroll
                for (int nn = 0; nn < 4; ++nn)
                    acc[m2][nn] = __builtin_amdgcn_mfma_f32_16x16x32_bf16(af[m2], bfr[nn], acc[m2][nn], 0, 0, 0);
        }
        __builtin_amdgcn_s_setprio(0);
        __syncthreads();                 // compute(t) done; sA free
        // ---- phase 2: gate + write sA(t+1) (waits xa at vmcnt(4), not 0)
        if (t + 1 < NT) {
            GATEW(xa);
        }
        __syncthreads();                 // sA(t+1) visible; B(t+1) drained here
    }

    // ---- epilogue: bf16 partials (summed + out_mu added in k_reduce3b)
    #pragma unroll
    for (int nn = 0; nn < 4; ++nn) {
        int col = cbase + wc * 64 + nn * 16 + lrow;
        #pragma unroll
        for (int m2 = 0; m2 < 4; ++m2) {
            int rbase = r0 + wr * 64 + m2 * 16 + lgrp * 4;
            #pragma unroll
            for (int j = 0; j < 4; ++j)
                P[(size_t)(rbase + j) * OUT_DIM + col] = f2bf(acc[m2][nn][j]);
        }
    }
}

// ---------------- reduce: out = PB0 + PB1 + PB2 + out_mu (bf16 partials) -----
__global__ __launch_bounds__(256) void k_reduce3b(float* __restrict__ out,
                                                  const ushort* __restrict__ PB0,
                                                  const ushort* __restrict__ PB1,
                                                  const ushort* __restrict__ PB2,
                                                  const float* __restrict__ out_mu) {
    int idx = blockIdx.x * 256 + threadIdx.x;       // 8-elem group, 524288 total
    uint4 a = *(const uint4*)(PB0 + (size_t)idx * 8);
    uint4 b = *(const uint4*)(PB1 + (size_t)idx * 8);
    uint4 c = *(const uint4*)(PB2 + (size_t)idx * 8);
    const float* om = out_mu + (idx & 511) * 8;
    float4 m0 = *(const float4*)om;
    float4 m1 = *(const float4*)(om + 4);
    float4 o0, o1;
    o0.x = bf2f((ushort)(a.x & 0xFFFF)) + bf2f((ushort)(b.x & 0xFFFF)) + bf2f((ushort)(c.x & 0xFFFF)) + m0.x;
    o0.y = bf2f((ushort)(a.x >> 16))    + bf2f((ushort)(b.x >> 16))    + bf2f((ushort)(c.x >> 16))    + m0.y;
    o0.z = bf2f((ushort)(a.y & 0xFFFF)) + bf2f((ushort)(b.y & 0xFFFF)) + bf2f((ushort)(c.y & 0xFFFF)) + m0.z;
    o0.w = bf2f((ushort)(a.y >> 16))    + bf2f((ushort)(b.y >> 16))    + bf2f((ushort)(c.y >> 16))    + m0.w;
    o1.x = bf2f((ushort)(a.z & 0xFFFF)) + bf2f((ushort)(b.z & 0xFFFF)) + bf2f((ushort)(c.z & 0xFFFF)) + m1.x;
    o1.y = bf2f((ushort)(a.z >> 16))    + bf2f((ushort)(b.z >> 16))    + bf2f((ushort)(c.z >> 16))    + m1.y;
    o1.z = bf2f((ushort)(a.w & 0xFFFF)) + bf2f((ushort)(b.w & 0xFFFF)) + bf2f((ushort)(c.w & 0xFFFF)) + m1.z;
    o1.w = bf2f((ushort)(a.w >> 16))    + bf2f((ushort)(b.w >> 16))    + bf2f((ushort)(c.w >> 16))    + m1.w;
    float* dst = out + (size_t)idx * 8;
    *(float4*)dst = o0;
    *(float4*)(dst + 4) = o1;
}

// ---------------- fallback: naive fp32 ---------------------------------------
__global__ __launch_bounds__(256) void k_naive(const float* __restrict__ x,
                                               const float* __restrict__ W,
                                               const float* __restrict__ th,
                                               const float* __restrict__ mu,
                                               const float* __restrict__ out_mu,
                                               float* __restrict__ out) {
    int idx = blockIdx.x * 256 + threadIdx.x;
    int r = idx >> 12;
    int c = idx & 4095;
    int n = c >> 7;
    float s = 0.f;
    for (int i = 0; i < I_DIM; ++i) {
        float xo = x[(size_t)r * I_DIM + i] - mu[i];
        if (fabsf(xo) >= th[i * N_STR + n])
            s += xo * W[(size_t)i * OUT_DIM + c];
    }
    out[idx] = s + out_mu[c];
}

extern "C" void kernel_launch(void* const* d_in, const int* in_sizes, int n_in,
                              void* d_out, int out_size, void* d_ws, size_t ws_size,
                              hipStream_t stream) {
    const float* x      = (const float*)d_in[0];
    const float* W      = (const float*)d_in[1];
    const float* th     = (const float*)d_in[2];
    const float* mu     = (const float*)d_in[3];
    const float* out_mu = (const float*)d_in[4];
    float* out = (float*)d_out;

    const size_t wT_b  = (size_t)OUT_DIM * I_DIM * sizeof(ushort);   // 32 MiB
    const size_t thT_b = (size_t)N_STR * I_DIM * sizeof(float);      // 0.5 MiB
    const size_t pb_b  = (size_t)R_TOTAL * OUT_DIM * sizeof(ushort); // 8 MiB each

    ushort* WT  = (ushort*)d_ws;
    float*  thT = (float*)((char*)d_ws + wT_b);
    ushort* PB0 = (ushort*)((char*)d_ws + wT_b + thT_b);
    ushort* PB1 = (ushort*)((char*)d_ws + wT_b + thT_b + pb_b);
    ushort* PB2 = (ushort*)((char*)d_ws + wT_b + thT_b + 2 * pb_b);

    if (ws_size >= wT_b + thT_b + 3 * pb_b) {
        k_prep7<<<64 + 4096, 256, 0, stream>>>(W, WT, th, thT);
        k_main14<<<768, 256, 0, stream>>>(x, WT, thT, mu, PB0, PB1, PB2);
        k_reduce3b<<<(R_TOTAL * OUT_DIM / 8) / 256, 256, 0, stream>>>(out, PB0, PB1, PB2, out_mu);
    } else {
        k_naive<<<(R_TOTAL * OUT_DIM) / 256, 256, 0, stream>>>(x, W, th, mu, out_mu, out);
    }
}

// Round 17
// 83.632 us; speedup vs baseline: 1.0925x; 1.0227x over previous
//
#include <hip/hip_runtime.h>
#include <hip/hip_bf16.h>
#include <stdint.h>

// Problem dims (fixed by reference)
#define R_TOTAL 1024      // B*S
#define I_DIM   4096
#define OUT_DIM 4096
#define N_STR   32
#define Q_DIM   128

typedef __attribute__((ext_vector_type(8))) __bf16 bf16x8;
typedef __attribute__((ext_vector_type(4))) float  f32x4;

__device__ __forceinline__ ushort f2bf(float f) {
    uint32_t u = __float_as_uint(f);
    uint32_t r = (u + 0x7fffu + ((u >> 16) & 1u)) >> 16;   // RNE
    return (ushort)r;
}

__device__ __forceinline__ float bf2f(ushort u) {
    return __uint_as_float((uint32_t)u << 16);
}

// gate two fp32 lanes (exact fp32 compare, as reference) and pack to 2 bf16
// via v_cvt_pk_bf16_f32 (RNE; dst.lo = src0, dst.hi = src1 — T12 recipe).
__device__ __forceinline__ uint32_t gate_pk(float x0, float x1,
                                            float m0, float m1,
                                            float t0, float t1) {
    float a = x0 - m0, b = x1 - m1;
    float ga = (fabsf(a) >= t0) ? a : 0.f;
    float gb = (fabsf(b) >= t1) ? b : 0.f;
    uint32_t r;
    asm("v_cvt_pk_bf16_f32 %0, %1, %2" : "=v"(r) : "v"(ga), "v"(gb));
    return r;
}

__device__ __forceinline__ void async16(void* lds, const void* g) {
    __builtin_amdgcn_global_load_lds(
        (const __attribute__((address_space(1))) unsigned int*)g,
        (__attribute__((address_space(3))) unsigned int*)lds, 16, 0, 0);
}

// ================= pre-pass bodies ===========================================

// W [I][OUT] f32 -> WT [OUT][I] bf16, one 64x64 tile
__device__ __forceinline__ void transpose_w_block(const float* __restrict__ W,
                                                  ushort* __restrict__ WT,
                                                  int c0, int i0, int t,
                                                  float (*tile)[65]) {
    {
        int dc4 = (t & 15) * 4;
        int di  = t >> 4;
        #pragma unroll
        for (int p = 0; p < 4; ++p) {
            int ii = di + p * 16;
            float4 v = *(const float4*)(W + (size_t)(i0 + ii) * OUT_DIM + c0 + dc4);
            tile[ii][dc4 + 0] = v.x; tile[ii][dc4 + 1] = v.y;
            tile[ii][dc4 + 2] = v.z; tile[ii][dc4 + 3] = v.w;
        }
    }
    __syncthreads();
    {
        int iq = (t & 15) * 4;
        int dc = t >> 4;
        #pragma unroll
        for (int p = 0; p < 4; ++p) {
            int cc = dc + p * 16;
            ushort4 o;
            o.x = f2bf(tile[iq + 0][cc]);
            o.y = f2bf(tile[iq + 1][cc]);
            o.z = f2bf(tile[iq + 2][cc]);
            o.w = f2bf(tile[iq + 3][cc]);
            *(ushort4*)(WT + (size_t)(c0 + cc) * I_DIM + i0 + iq) = o;
        }
    }
}

// th [I][N] f32 -> thT [N][I] f32, one 64(i) x 32(n) tile via LDS
__device__ __forceinline__ void transpose_th_block(const float* __restrict__ th,
                                                   float* __restrict__ thT,
                                                   int i0, int t, float* tile) {
    {
        int ri = t >> 2;
        int nc = (t & 3) * 8;
        float4 v0 = *(const float4*)(th + (size_t)(i0 + ri) * N_STR + nc);
        float4 v1 = *(const float4*)(th + (size_t)(i0 + ri) * N_STR + nc + 4);
        tile[ri * 33 + nc + 0] = v0.x; tile[ri * 33 + nc + 1] = v0.y;
        tile[ri * 33 + nc + 2] = v0.z; tile[ri * 33 + nc + 3] = v0.w;
        tile[ri * 33 + nc + 4] = v1.x; tile[ri * 33 + nc + 5] = v1.y;
        tile[ri * 33 + nc + 6] = v1.z; tile[ri * 33 + nc + 7] = v1.w;
    }
    __syncthreads();
    {
        int n  = t >> 3;
        int di = (t & 7) * 8;
        float4 o0, o1;
        o0.x = tile[(di + 0) * 33 + n]; o0.y = tile[(di + 1) * 33 + n];
        o0.z = tile[(di + 2) * 33 + n]; o0.w = tile[(di + 3) * 33 + n];
        o1.x = tile[(di + 4) * 33 + n]; o1.y = tile[(di + 5) * 33 + n];
        o1.z = tile[(di + 6) * 33 + n]; o1.w = tile[(di + 7) * 33 + n];
        *(float4*)(thT + (size_t)n * I_DIM + i0 + di) = o0;
        *(float4*)(thT + (size_t)n * I_DIM + i0 + di + 4) = o1;
    }
}

// ---------------- merged pre-pass: th-transpose (0..63) + W-transpose --------
__global__ __launch_bounds__(256) void k_prep7(const float* __restrict__ W,
                                               ushort* __restrict__ WT,
                                               const float* __restrict__ th,
                                               float* __restrict__ thT) {
    __shared__ __align__(16) float smem[64 * 65];
    int b = blockIdx.x;
    int t = threadIdx.x;
    if (b < 64) {
        transpose_th_block(th, thT, b * 64, t, smem);
    } else {
        int tb = b - 64;
        transpose_w_block(W, WT, (tb & 63) * 64, (tb >> 6) * 64, t,
                          (float (*)[65])smem);
    }
}

// ---------------- main v12 (session best): inline gate; x issued in phase 1 --
// tile 128x128, 4 waves of 64x64, BK=64. sA single (16K) + sB dbuf (32K)
// = 48 KB -> 3 blocks/CU. Split-K=3 uneven: 22/21/21 steps of BK=64.
// Phase 1 issues B(t+1) DMA + A(t+1) x/th/mu reg loads; the 32-MFMA compute
// phase covers their latency before barrier-1's vmcnt(0) drain. Phase 2 is
// the pure-VALU gate + swizzled sA write. R14 XCD map (stripe-group -> XCD:
// WT slice 4 MB = L2-fit; proven best of 3 maps tried).

#define LOADX(XA, OFF)                                              \
    do {                                                            \
        _Pragma("unroll")                                           \
        for (int p = 0; p < 4; ++p) {                               \
            XA[p][0] = *(const float4*)(pX[p] + (OFF));             \
            XA[p][1] = *((const float4*)(pX[p] + (OFF)) + 1);       \
        }                                                           \
    } while (0)

#define GATEW(XA)                                                                        \
    do {                                                                                 \
        _Pragma("unroll")                                                                \
        for (int p = 0; p < 4; ++p) {                                                    \
            uint4 z;                                                                     \
            z.x = gate_pk(XA[p][0].x, XA[p][0].y, muv[0].x, muv[0].y, thv[0].x, thv[0].y); \
            z.y = gate_pk(XA[p][0].z, XA[p][0].w, muv[0].z, muv[0].w, thv[0].z, thv[0].w); \
            z.z = gate_pk(XA[p][1].x, XA[p][1].y, muv[1].x, muv[1].y, thv[1].x, thv[1].y); \
            z.w = gate_pk(XA[p][1].z, XA[p][1].w, muv[1].z, muv[1].w, thv[1].z, thv[1].w); \
            *(uint4*)((char*)sA + awz[p]) = z;                                           \
        }                                                                                \
    } while (0)

__global__ __launch_bounds__(256, 3) void k_main12(const float* __restrict__ x,
                                                   const ushort* __restrict__ WT,
                                                   const float* __restrict__ thT,
                                                   const float* __restrict__ mu,
                                                   ushort* __restrict__ PB0,
                                                   ushort* __restrict__ PB1,
                                                   ushort* __restrict__ PB2) {
    __shared__ ushort sA[128 * 64];      // 16 KB (single)
    __shared__ ushort sB[2][128 * 64];   // 16 KB each

    int bid  = blockIdx.x;               // 0..767
    int xcd  = bid & 7;
    int slot = bid >> 3;                 // 0..95
    int n    = xcd * 4 + (slot & 3);     // stripe (XCD-local group of 4)
    int rt   = (slot >> 2) & 7;          // row tile 0..7
    int kq   = slot >> 5;                // 0..2
    int r0   = rt * 128;
    int k0   = (kq == 0) ? 0 : (kq == 1) ? 1408 : 2752;
    int NT   = (kq == 0) ? 22 : 21;
    int cbase = n * Q_DIM;
    ushort* P = (kq == 0) ? PB0 : (kq == 1) ? PB1 : PB2;

    int tid  = threadIdx.x;
    int lane = tid & 63;
    int wave = tid >> 6;                 // 0..3
    int wr   = wave >> 1;                // 0..1 : 64-row group
    int wc   = wave & 1;                 // 0..1 : 64-col group
    int lrow = lane & 15;
    int lgrp = lane >> 4;

    // ---- A staging maps: pass p: row = p*32 + (tid>>3), 8 consecutive k
    const float* pX[4];
    int awz[4];
    const int ak = (tid & 7) * 8;
    {
        int ar = tid >> 3;
        #pragma unroll
        for (int p = 0; p < 4; ++p) {
            int row = p * 32 + ar;
            pX[p] = x + (size_t)(r0 + row) * I_DIM + k0 + ak;
            awz[p] = row * 128 + ((ak * 2) ^ ((row & 7) << 4));
        }
    }
    const float* pTH = thT + (size_t)n * I_DIM + k0 + ak;
    const float* pMU = mu + k0 + ak;

    // ---- B staging maps: 16 chunks of 1KB; pre-swizzled source
    const char* pBq[4];
    int ldsBo[4];
    #pragma unroll
    for (int q = 0; q < 4; ++q) {
        int chunk = wave * 4 + q;
        int col = chunk * 8 + (lane >> 3);
        pBq[q] = (const char*)WT + (size_t)(cbase + col) * (I_DIM * 2)
               + (size_t)k0 * 2 + (((lane & 7) ^ (lane >> 3)) << 4);
        ldsBo[q] = chunk * 1024;
    }

    f32x4 acc[4][4];
    #pragma unroll
    for (int m2 = 0; m2 < 4; ++m2)
        #pragma unroll
        for (int nn = 0; nn < 4; ++nn)
            acc[m2][nn] = (f32x4){0.f, 0.f, 0.f, 0.f};

    float4 xa[4][2], thv[2], muv[2];     // single-depth A-regs (phase1 -> phase2)

    // ---- prologue: A(0) regs + th/mu(0); B0 DMA; gate+write sA(0); barrier
    LOADX(xa, 0);
    thv[0] = *(const float4*)pTH; thv[1] = *((const float4*)pTH + 1);
    muv[0] = *(const float4*)pMU; muv[1] = *((const float4*)pMU + 1);
    #pragma unroll
    for (int q = 0; q < 4; ++q) async16((char*)sB[0] + ldsBo[q], pBq[q]);
    GATEW(xa);                           // write sA(0)
    __syncthreads();                     // sA(0), sB[0] ready

    for (int t = 0; t < NT; ++t) {
        // ---- phase 1: issue B(t+1) DMA AND A(t+1) x/th/mu loads; then compute
        if (t + 1 < NT) {
            #pragma unroll
            for (int q = 0; q < 4; ++q)
                async16((char*)sB[(t + 1) & 1] + ldsBo[q],
                        pBq[q] + (size_t)(t + 1) * 128);
            int o1 = (t + 1) * 64;
            LOADX(xa, o1);
            thv[0] = *(const float4*)(pTH + o1);
            thv[1] = *((const float4*)(pTH + o1) + 1);
            muv[0] = *(const float4*)(pMU + o1);
            muv[1] = *((const float4*)(pMU + o1) + 1);
        }
        // ---- compute tile t (sA single, sB[t&1]) — covers the loads above
        const char* sAc = (const char*)sA;
        const char* sBc = (const char*)sB[t & 1];
        __builtin_amdgcn_s_setprio(1);
        #pragma unroll
        for (int ks = 0; ks < 2; ++ks) {
            int kb = ks * 64 + (lgrp << 4);
            bf16x8 af[4], bfr[4];
            #pragma unroll
            for (int m2 = 0; m2 < 4; ++m2) {
                int row = wr * 64 + m2 * 16 + lrow;
                af[m2] = *(const bf16x8*)(sAc + row * 128 + (kb ^ ((row & 7) << 4)));
            }
            #pragma unroll
            for (int nn = 0; nn < 4; ++nn) {
                int col = wc * 64 + nn * 16 + lrow;
                bfr[nn] = *(const bf16x8*)(sBc + col * 128 + (kb ^ ((col & 7) << 4)));
            }
            #pragma unroll
            for (int m2 = 0; m2 < 4; ++m2)
                #pragma unroll
                for (int nn = 0; nn < 4; ++nn)
                    acc[m2][nn] = __builtin_amdgcn_mfma_f32_16x16x32_bf16(af[m2], bfr[nn], acc[m2][nn], 0, 0, 0);
        }
        __builtin_amdgcn_s_setprio(0);
        __syncthreads();                 // compute done; B(t+1) + xa drained
        // ---- phase 2: gate + write sA(t+1) (pure VALU + ds_write)
        if (t + 1 < NT) {
            GATEW(xa);
        }
        __syncthreads();                 // sA(t+1) visible (lgkm-only drain)
    }

    // ---- epilogue: bf16 partials (summed + out_mu added in k_reduce3b)
    #pragma unroll
    for (int nn = 0; nn < 4; ++nn) {
        int col = cbase + wc * 64 + nn * 16 + lrow;
        #pragma unroll
        for (int m2 = 0; m2 < 4; ++m2) {
            int rbase = r0 + wr * 64 + m2 * 16 + lgrp * 4;
            #pragma unroll
            for (int j = 0; j < 4; ++j)
                P[(size_t)(rbase + j) * OUT_DIM + col] = f2bf(acc[m2][nn][j]);
        }
    }
}

// ---------------- reduce: out = PB0 + PB1 + PB2 + out_mu (bf16 partials) -----
__global__ __launch_bounds__(256) void k_reduce3b(float* __restrict__ out,
                                                  const ushort* __restrict__ PB0,
                                                  const ushort* __restrict__ PB1,
                                                  const ushort* __restrict__ PB2,
                                                  const float* __restrict__ out_mu) {
    int idx = blockIdx.x * 256 + threadIdx.x;       // 8-elem group, 524288 total
    uint4 a = *(const uint4*)(PB0 + (size_t)idx * 8);
    uint4 b = *(const uint4*)(PB1 + (size_t)idx * 8);
    uint4 c = *(const uint4*)(PB2 + (size_t)idx * 8);
    const float* om = out_mu + (idx & 511) * 8;
    float4 m0 = *(const float4*)om;
    float4 m1 = *(const float4*)(om + 4);
    float4 o0, o1;
    o0.x = bf2f((ushort)(a.x & 0xFFFF)) + bf2f((ushort)(b.x & 0xFFFF)) + bf2f((ushort)(c.x & 0xFFFF)) + m0.x;
    o0.y = bf2f((ushort)(a.x >> 16))    + bf2f((ushort)(b.x >> 16))    + bf2f((ushort)(c.x >> 16))    + m0.y;
    o0.z = bf2f((ushort)(a.y & 0xFFFF)) + bf2f((ushort)(b.y & 0xFFFF)) + bf2f((ushort)(c.y & 0xFFFF)) + m0.z;
    o0.w = bf2f((ushort)(a.y >> 16))    + bf2f((ushort)(b.y >> 16))    + bf2f((ushort)(c.y >> 16))    + m0.w;
    o1.x = bf2f((ushort)(a.z & 0xFFFF)) + bf2f((ushort)(b.z & 0xFFFF)) + bf2f((ushort)(c.z & 0xFFFF)) + m1.x;
    o1.y = bf2f((ushort)(a.z >> 16))    + bf2f((ushort)(b.z >> 16))    + bf2f((ushort)(c.z >> 16))    + m1.y;
    o1.z = bf2f((ushort)(a.w & 0xFFFF)) + bf2f((ushort)(b.w & 0xFFFF)) + bf2f((ushort)(c.w & 0xFFFF)) + m1.z;
    o1.w = bf2f((ushort)(a.w >> 16))    + bf2f((ushort)(b.w >> 16))    + bf2f((ushort)(c.w >> 16))    + m1.w;
    float* dst = out + (size_t)idx * 8;
    *(float4*)dst = o0;
    *(float4*)(dst + 4) = o1;
}

// ---------------- fallback: naive fp32 ---------------------------------------
__global__ __launch_bounds__(256) void k_naive(const float* __restrict__ x,
                                               const float* __restrict__ W,
                                               const float* __restrict__ th,
                                               const float* __restrict__ mu,
                                               const float* __restrict__ out_mu,
                                               float* __restrict__ out) {
    int idx = blockIdx.x * 256 + threadIdx.x;
    int r = idx >> 12;
    int c = idx & 4095;
    int n = c >> 7;
    float s = 0.f;
    for (int i = 0; i < I_DIM; ++i) {
        float xo = x[(size_t)r * I_DIM + i] - mu[i];
        if (fabsf(xo) >= th[i * N_STR + n])
            s += xo * W[(size_t)i * OUT_DIM + c];
    }
    out[idx] = s + out_mu[c];
}

extern "C" void kernel_launch(void* const* d_in, const int* in_sizes, int n_in,
                              void* d_out, int out_size, void* d_ws, size_t ws_size,
                              hipStream_t stream) {
    const float* x      = (const float*)d_in[0];
    const float* W      = (const float*)d_in[1];
    const float* th     = (const float*)d_in[2];
    const float* mu     = (const float*)d_in[3];
    const float* out_mu = (const float*)d_in[4];
    float* out = (float*)d_out;

    const size_t wT_b  = (size_t)OUT_DIM * I_DIM * sizeof(ushort);   // 32 MiB
    const size_t thT_b = (size_t)N_STR * I_DIM * sizeof(float);      // 0.5 MiB
    const size_t pb_b  = (size_t)R_TOTAL * OUT_DIM * sizeof(ushort); // 8 MiB each

    ushort* WT  = (ushort*)d_ws;
    float*  thT = (float*)((char*)d_ws + wT_b);
    ushort* PB0 = (ushort*)((char*)d_ws + wT_b + thT_b);
    ushort* PB1 = (ushort*)((char*)d_ws + wT_b + thT_b + pb_b);
    ushort* PB2 = (ushort*)((char*)d_ws + wT_b + thT_b + 2 * pb_b);

    if (ws_size >= wT_b + thT_b + 3 * pb_b) {
        k_prep7<<<64 + 4096, 256, 0, stream>>>(W, WT, th, thT);
        k_main12<<<768, 256, 0, stream>>>(x, WT, thT, mu, PB0, PB1, PB2);
        k_reduce3b<<<(R_TOTAL * OUT_DIM / 8) / 256, 256, 0, stream>>>(out, PB0, PB1, PB2, out_mu);
    } else {
        k_naive<<<(R_TOTAL * OUT_DIM) / 256, 256, 0, stream>>>(x, W, th, mu, out_mu, out);
    }
}